// Round 1
// baseline (1029.514 us; speedup 1.0000x reference)
//
#include <hip/hip_runtime.h>
#include <hip/hip_cooperative_groups.h>
#include <math.h>

namespace cg = cooperative_groups;

constexpr int NN  = 4096;   // nodes
constexpr int CC  = 256;    // channels
constexpr int EE0 = 65536;  // edges w/o self loops
constexpr int EE  = 69632;  // EE0 + NN
constexpr int KK  = 2048;   // pooled nodes
constexpr int NB  = 1024;   // cooperative grid (4 blocks/CU * 256 CU)
constexpr int NT  = 256;

__device__ __forceinline__ void edge_ij(const int* __restrict__ ei, int e, int& i, int& j) {
    if (e < EE0) { i = ei[e]; j = ei[EE0 + e]; }
    else         { i = e - EE0; j = i; }
}

// ============================ cooperative mega-kernel ============================
struct Params {
    const float* x; const int* ei;
    const float* Wq; const float* bq; const float* gat_w; const float* gat_b;
    const float* le1_w; const float* le1_b; const float* le2_w;
    const float* le3_w; const float* le3_b;
    float* xout; float* Ead; float* operm;
    float* score32; float* out32;
    double* a64; double* b64; double* l3v; double* zlog;
    double* wv; double* consts;
    int* cnt_i; int* cnt_j;
    int* off_i; int* pos_i; int* lst_i;
    int* off_j; int* pos_j; int* lst_j;
    int* n_idx; int* perm; int* colj; float* svalj;
};

union ShMem {
    struct { double wred[4]; } ph0;
    struct { int lds[256]; } ph2;
    struct {
        int sj[128];
        double ssc[128];
        double mz[2];
        union { float4 m4[4][64]; double d[4][CC]; } red;
    } at;                                  // ~9.75 KB (max member)
    struct { int red[4]; int rr; } rk;
    struct { float row[KK]; } ej;          // 8 KB
};

__global__ __launch_bounds__(NT, 4) void mega(Params P) {
    __shared__ ShMem sh;
    cg::grid_group grid = cg::this_grid();
    const int bid = blockIdx.x, t = threadIdx.x;
    const int g = t >> 6, l = t & 63;

    // ---- phase 0: wv[k]=Wq[k,:].gat_w[:C], consts, zero counters (replaces memset) ----
    if (bid < CC) {
        double s = (double)P.Wq[bid * CC + t] * (double)P.gat_w[t];
        #pragma unroll
        for (int d = 32; d > 0; d >>= 1) s += __shfl_down(s, d, 64);
        if (l == 0) sh.ph0.wred[g] = s;
        __syncthreads();
        if (t == 0) {
            P.wv[bid] = sh.ph0.wred[0] + sh.ph0.wred[1] + sh.ph0.wred[2] + sh.ph0.wred[3];
            if (bid == 0) {
                double cb = 0.0;
                for (int q = 0; q < CC; ++q) cb += (double)P.bq[q] * (double)P.gat_w[q];
                P.consts[0] = cb + (double)P.gat_b[0];
            }
        }
    } else if (bid < CC + 32) {
        P.cnt_i[(bid - CC) * NT + t] = 0;   // cnt_i & cnt_j are contiguous 2*NN ints
    }
    grid.sync();

    // ---- phase 1: degree count ----
    {
        int e = bid * NT + t;
        if (e < EE) {
            int i, j; edge_ij(P.ei, e, i, j);
            atomicAdd(&P.cnt_i[i], 1);
            atomicAdd(&P.cnt_j[j], 1);
        }
    }
    grid.sync();

    // ---- phase 2: two exclusive scans (blocks 0 & 1) ----
    if (bid < 2) {
        const int* cnt = bid ? P.cnt_j : P.cnt_i;
        int* off = bid ? P.off_j : P.off_i;
        int* pos = bid ? P.pos_j : P.pos_i;
        int b = t * 16;
        int c[16]; int s = 0;
        #pragma unroll
        for (int q = 0; q < 16; ++q) { c[q] = cnt[b + q]; s += c[q]; }
        sh.ph2.lds[t] = s;
        __syncthreads();
        for (int d = 1; d < 256; d <<= 1) {
            int add = (t >= d) ? sh.ph2.lds[t - d] : 0;
            __syncthreads();
            sh.ph2.lds[t] += add;
            __syncthreads();
        }
        int run = sh.ph2.lds[t] - s;
        #pragma unroll
        for (int q = 0; q < 16; ++q) { off[b + q] = run; pos[b + q] = run; run += c[q]; }
        if (t == 255) off[NN] = run;
    }
    grid.sync();

    // ---- phase 3: scatter into CSR lists ----
    {
        int e = bid * NT + t;
        if (e < EE) {
            int i, j; edge_ij(P.ei, e, i, j);
            P.lst_i[atomicAdd(&P.pos_i[i], 1)] = e;
            P.lst_j[atomicAdd(&P.pos_j[j], 1)] = e;
        }
    }
    grid.sync();

    // ---- phase 4: fused Xq-max + per-edge beta + softmax + out-gather + LEConv dots ----
    // (was k_xqab + k_softout; second x-row gather hits L1 primed by the max pass)
    {
        const float* gw2 = P.gat_w + CC;
        const double cst = P.consts[0];
        for (int n = bid; n < NN; n += NB) {      // exactly 4 iterations per block
            int s0 = P.off_i[n], deg = P.off_i[n + 1] - s0;   // deg <= 128 (verified prior session)
            float4 mx = make_float4(-INFINITY, -INFINITY, -INFINITY, -INFINITY);
            for (int p = g; p < deg; p += 4) {
                int e = P.lst_i[s0 + p]; int i, j; edge_ij(P.ei, e, i, j);
                float4 v = ((const float4*)(P.x + (size_t)j * CC))[l];
                mx.x = fmaxf(mx.x, v.x); mx.y = fmaxf(mx.y, v.y);
                mx.z = fmaxf(mx.z, v.z); mx.w = fmaxf(mx.w, v.w);
                double d = (double)v.x * (double)gw2[4 * l]     + (double)v.y * (double)gw2[4 * l + 1]
                         + (double)v.z * (double)gw2[4 * l + 2] + (double)v.w * (double)gw2[4 * l + 3];
                #pragma unroll
                for (int dd = 32; dd > 0; dd >>= 1) d += __shfl_down(d, dd, 64);
                if (l == 0) { sh.at.sj[p] = j; sh.at.ssc[p] = d; }   // beta_e
            }
            sh.at.red.m4[g][l] = mx;
            __syncthreads();
            if (g == 0) {
                float4 a = sh.at.red.m4[0][l], b = sh.at.red.m4[1][l];
                float4 c2 = sh.at.red.m4[2][l], d4 = sh.at.red.m4[3][l];
                float m0 = fmaxf(fmaxf(a.x, b.x), fmaxf(c2.x, d4.x));
                float m1 = fmaxf(fmaxf(a.y, b.y), fmaxf(c2.y, d4.y));
                float m2 = fmaxf(fmaxf(a.z, b.z), fmaxf(c2.z, d4.z));
                float m3 = fmaxf(fmaxf(a.w, b.w), fmaxf(c2.w, d4.w));
                double alph = (double)m0 * P.wv[4 * l]     + (double)m1 * P.wv[4 * l + 1]
                            + (double)m2 * P.wv[4 * l + 2] + (double)m3 * P.wv[4 * l + 3];
                #pragma unroll
                for (int dd = 32; dd > 0; dd >>= 1) alph += __shfl_down(alph, dd, 64);
                if (l == 0) sh.at.mz[0] = alph + cst;
            }
            __syncthreads();
            double an = sh.at.mz[0];
            for (int p = t; p < deg; p += NT) {
                double v = an + sh.at.ssc[p];
                sh.at.ssc[p] = v > 0.0 ? v : 0.2 * v;
            }
            __syncthreads();
            if (t < 64) {
                double mm = -1e300;
                for (int p = l; p < deg; p += 64) mm = fmax(mm, sh.at.ssc[p]);
                #pragma unroll
                for (int d = 32; d > 0; d >>= 1) mm = fmax(mm, __shfl_xor(mm, d, 64));
                double z = 0.0;
                for (int p = l; p < deg; p += 64) z += exp(sh.at.ssc[p] - mm);
                #pragma unroll
                for (int d = 32; d > 0; d >>= 1) z += __shfl_xor(z, d, 64);
                if (l == 0) { sh.at.mz[0] = mm; sh.at.mz[1] = 1.0 / z; }
            }
            __syncthreads();
            double mm = sh.at.mz[0], inv = sh.at.mz[1];
            for (int p = t; p < deg; p += NT) {
                double sc = exp(sh.at.ssc[p] - mm) * inv;
                sh.at.ssc[p] = sc;
                P.score32[P.lst_i[s0 + p]] = (float)sc;
            }
            __syncthreads();
            double a0 = 0, a1 = 0, a2 = 0, a3 = 0;
            for (int p = g; p < deg; p += 4) {
                double sc = sh.at.ssc[p];
                float4 v = ((const float4*)(P.x + (size_t)sh.at.sj[p] * CC))[l];
                a0 += sc * (double)v.x; a1 += sc * (double)v.y;
                a2 += sc * (double)v.z; a3 += sc * (double)v.w;
            }
            sh.at.red.d[g][4 * l + 0] = a0; sh.at.red.d[g][4 * l + 1] = a1;
            sh.at.red.d[g][4 * l + 2] = a2; sh.at.red.d[g][4 * l + 3] = a3;
            __syncthreads();
            if (g == 0) {
                double o0 = sh.at.red.d[0][4*l]   + sh.at.red.d[1][4*l]   + sh.at.red.d[2][4*l]   + sh.at.red.d[3][4*l];
                double o1 = sh.at.red.d[0][4*l+1] + sh.at.red.d[1][4*l+1] + sh.at.red.d[2][4*l+1] + sh.at.red.d[3][4*l+1];
                double o2 = sh.at.red.d[0][4*l+2] + sh.at.red.d[1][4*l+2] + sh.at.red.d[2][4*l+2] + sh.at.red.d[3][4*l+2];
                double o3 = sh.at.red.d[0][4*l+3] + sh.at.red.d[1][4*l+3] + sh.at.red.d[2][4*l+3] + sh.at.red.d[3][4*l+3];
                float4 ov; ov.x = (float)o0; ov.y = (float)o1; ov.z = (float)o2; ov.w = (float)o3;
                ((float4*)(P.out32 + (size_t)n * CC))[l] = ov;
                float4 w1 = ((const float4*)P.le1_w)[l];
                float4 w2 = ((const float4*)P.le2_w)[l];
                float4 w3 = ((const float4*)P.le3_w)[l];
                double s1 = o0 * (double)w1.x + o1 * (double)w1.y + o2 * (double)w1.z + o3 * (double)w1.w;
                double s2 = o0 * (double)w2.x + o1 * (double)w2.y + o2 * (double)w2.z + o3 * (double)w2.w;
                double s3 = o0 * (double)w3.x + o1 * (double)w3.y + o2 * (double)w3.z + o3 * (double)w3.w;
                #pragma unroll
                for (int dd = 32; dd > 0; dd >>= 1) {
                    s1 += __shfl_down(s1, dd, 64);
                    s2 += __shfl_down(s2, dd, 64);
                    s3 += __shfl_down(s3, dd, 64);
                }
                if (l == 0) {
                    P.a64[n] = s1 + (double)P.le1_b[0];
                    P.b64[n] = s2;
                    P.l3v[n] = s3 + (double)P.le3_b[0];
                }
            }
            __syncthreads();
        }
    }
    grid.sync();

    // ---- phase 5: zlog (one wave per node: NB*4 == NN) ----
    {
        int n = bid * 4 + g;
        int s = P.off_i[n], e_ = P.off_i[n + 1];
        double acc = 0.0;
        for (int p = s + l; p < e_; p += 64) {
            int e = P.lst_i[p]; int i, j; edge_ij(P.ei, e, i, j);
            acc += P.a64[j];
        }
        #pragma unroll
        for (int d = 32; d > 0; d >>= 1) acc += __shfl_xor(acc, d, 64);
        if (l == 0) P.zlog[n] = acc - (double)(e_ - s) * P.b64[n] + P.l3v[n];
    }
    grid.sync();

    // ---- phase 6: rank-by-counting + n_idx (folds old memset) + x_out ----
    for (int n = bid; n < NN; n += NB) {
        double zn = P.zlog[n];
        int cnt = 0;
        #pragma unroll
        for (int u = 0; u < NN / NT; ++u) {
            int mIdx = t + u * NT;
            double zm = P.zlog[mIdx];
            cnt += ((zm > zn) || (zm == zn && mIdx < n)) ? 1 : 0;
        }
        #pragma unroll
        for (int d = 32; d > 0; d >>= 1) cnt += __shfl_down(cnt, d, 64);
        if (l == 0) sh.rk.red[g] = cnt;
        __syncthreads();
        if (t == 0) {
            int r = sh.rk.red[0] + sh.rk.red[1] + sh.rk.red[2] + sh.rk.red[3];
            sh.rk.rr = r;
            if (r < KK) { P.perm[r] = n; P.n_idx[n] = r; P.operm[r] = (float)n; }
            else P.n_idx[n] = -1;
        }
        __syncthreads();
        int r = sh.rk.rr;
        if (r < KK) {
            double fit = 1.0 / (1.0 + exp(-zn));
            P.xout[(size_t)r * CC + t] = (float)((double)P.out32[(size_t)n * CC + t] * fit);
        }
        __syncthreads();
    }
    grid.sync();

    // ---- phase 7: colval ----
    {
        int p = bid * NT + t;
        if (p < EE) {
            int e = P.lst_j[p]; int i, j; edge_ij(P.ei, e, i, j);
            P.colj[p] = P.n_idx[i];
            P.svalj[p] = P.score32[e];
        }
    }
    grid.sync();

    // ---- phase 8: Eadj rows via LDS accumulation ----
    for (int r = bid; r < KK; r += NB) {         // exactly 2 iterations per block
        float4 z4 = make_float4(0.f, 0.f, 0.f, 0.f);
        for (int c = t; c < KK / 4; c += NT) ((float4*)sh.ej.row)[c] = z4;
        __syncthreads();
        int n = P.perm[r];
        int s = P.off_i[n], e_ = P.off_i[n + 1];
        int grp = t >> 5, lane = t & 31;
        for (int p = s + grp; p < e_; p += 8) {
            int e = P.lst_i[p]; int i, j; edge_ij(P.ei, e, i, j);
            float s1 = P.score32[e];
            int q0 = P.off_j[j], q1 = P.off_j[j + 1];
            for (int q = q0 + lane; q < q1; q += 32) {
                int c = P.colj[q];
                if (c >= 0) atomicAdd(&sh.ej.row[c], s1 * P.svalj[q]);
            }
        }
        __syncthreads();
        float* __restrict__ erow = P.Ead + (size_t)r * KK;
        for (int c4 = t; c4 < KK / 4; c4 += NT) {
            float4 v = ((float4*)sh.ej.row)[c4];
            int base = c4 * 4, dr = r - base;
            if (dr >= 0 && dr < 4) ((float*)&v)[dr] = 1.0f;
            ((float4*)erow)[c4] = v;
        }
        __syncthreads();
    }
}

// ============================ fallback: verified 9-kernel path ============================
__global__ __launch_bounds__(256) void k_init(const int* __restrict__ ei, int* cnt_i, int* cnt_j,
                                              const float* __restrict__ Wq, const float* __restrict__ bq,
                                              const float* __restrict__ gat_w, const float* __restrict__ gat_b,
                                              double* wv, double* consts, int EB) {
    if ((int)blockIdx.x < EB) {
        int e = blockIdx.x * 256 + threadIdx.x;
        if (e >= EE) return;
        int i, j; edge_ij(ei, e, i, j);
        atomicAdd(&cnt_i[i], 1);
        atomicAdd(&cnt_j[j], 1);
        return;
    }
    int k = blockIdx.x - EB, c = threadIdx.x;
    double s = (double)Wq[k * CC + c] * (double)gat_w[c];
    #pragma unroll
    for (int d = 32; d > 0; d >>= 1) s += __shfl_down(s, d, 64);
    __shared__ double red[4];
    if ((c & 63) == 0) red[c >> 6] = s;
    __syncthreads();
    if (c == 0) wv[k] = red[0] + red[1] + red[2] + red[3];
    if (k == 0 && c == 0) {
        double cb = 0.0;
        for (int q = 0; q < CC; ++q) cb += (double)bq[q] * (double)gat_w[q];
        consts[0] = cb + (double)gat_b[0];
    }
}

__global__ __launch_bounds__(1024) void k_scan(const int* cnt_i, int* off_i, int* pos_i,
                                               const int* cnt_j, int* off_j, int* pos_j) {
    const int* cnt = blockIdx.x ? cnt_j : cnt_i;
    int* off = blockIdx.x ? off_j : off_i;
    int* pos = blockIdx.x ? pos_j : pos_i;
    __shared__ int lds[1024];
    int t = threadIdx.x;
    int b = t * 4;
    int c0 = cnt[b], c1 = cnt[b + 1], c2 = cnt[b + 2], c3 = cnt[b + 3];
    int s = c0 + c1 + c2 + c3;
    lds[t] = s;
    __syncthreads();
    for (int d = 1; d < 1024; d <<= 1) {
        int add = (t >= d) ? lds[t - d] : 0;
        __syncthreads();
        lds[t] += add;
        __syncthreads();
    }
    int excl = lds[t] - s;
    int o0 = excl, o1 = o0 + c0, o2 = o1 + c1, o3 = o2 + c2;
    off[b] = o0; off[b + 1] = o1; off[b + 2] = o2; off[b + 3] = o3;
    pos[b] = o0; pos[b + 1] = o1; pos[b + 2] = o2; pos[b + 3] = o3;
    if (t == 1023) off[NN] = o3 + c3;
}

__global__ void k_scatter(const int* __restrict__ ei, int* pos_i, int* lst_i,
                          int* pos_j, int* lst_j) {
    int e = blockIdx.x * blockDim.x + threadIdx.x;
    if (e >= EE) return;
    int i, j; edge_ij(ei, e, i, j);
    lst_i[atomicAdd(&pos_i[i], 1)] = e;
    lst_j[atomicAdd(&pos_j[j], 1)] = e;
}

__global__ __launch_bounds__(256) void k_xqab(const float* __restrict__ x, const int* __restrict__ ei,
                                              const int* __restrict__ off_i, const int* __restrict__ lst_i,
                                              const double* __restrict__ wv, const float* __restrict__ gat_w,
                                              double* alpha, double* beta) {
    int n = blockIdx.x, t = threadIdx.x, g = t >> 6, l = t & 63;
    int s = off_i[n], e_ = off_i[n + 1];
    float4 m = make_float4(-INFINITY, -INFINITY, -INFINITY, -INFINITY);
    for (int p = s + g; p < e_; p += 4) {
        int e = lst_i[p]; int i, j; edge_ij(ei, e, i, j);
        float4 v = ((const float4*)(x + (size_t)j * CC))[l];
        m.x = fmaxf(m.x, v.x); m.y = fmaxf(m.y, v.y);
        m.z = fmaxf(m.z, v.z); m.w = fmaxf(m.w, v.w);
    }
    __shared__ float4 red[4][64];
    red[g][l] = m;
    __syncthreads();
    if (g == 0) {
        float4 a = red[0][l], b = red[1][l], c2 = red[2][l], d4 = red[3][l];
        m.x = fmaxf(fmaxf(a.x, b.x), fmaxf(c2.x, d4.x));
        m.y = fmaxf(fmaxf(a.y, b.y), fmaxf(c2.y, d4.y));
        m.z = fmaxf(fmaxf(a.z, b.z), fmaxf(c2.z, d4.z));
        m.w = fmaxf(fmaxf(a.w, b.w), fmaxf(c2.w, d4.w));
        double alph = (double)m.x * wv[4 * l] + (double)m.y * wv[4 * l + 1]
                    + (double)m.z * wv[4 * l + 2] + (double)m.w * wv[4 * l + 3];
        float4 xn = ((const float4*)(x + (size_t)n * CC))[l];
        const float* gw2 = gat_w + CC;
        double bet = (double)xn.x * (double)gw2[4 * l] + (double)xn.y * (double)gw2[4 * l + 1]
                   + (double)xn.z * (double)gw2[4 * l + 2] + (double)xn.w * (double)gw2[4 * l + 3];
        #pragma unroll
        for (int d = 32; d > 0; d >>= 1) {
            alph += __shfl_down(alph, d, 64);
            bet  += __shfl_down(bet, d, 64);
        }
        if (l == 0) { alpha[n] = alph; beta[n] = bet; }
    }
}

__global__ __launch_bounds__(256) void k_softout(const float* __restrict__ x, const int* __restrict__ ei,
                                                 const int* __restrict__ off_i, const int* __restrict__ lst_i,
                                                 const double* __restrict__ alpha, const double* __restrict__ beta,
                                                 const double* __restrict__ consts,
                                                 const float* __restrict__ le1_w, const float* __restrict__ le1_b,
                                                 const float* __restrict__ le2_w,
                                                 const float* __restrict__ le3_w, const float* __restrict__ le3_b,
                                                 float* __restrict__ score32, double* __restrict__ out64,
                                                 double* a64, double* b64, double* l3v) {
    __shared__ int    sj[128];
    __shared__ double ssc[128];
    __shared__ double mz[2];
    __shared__ double red[4][CC];
    int n = blockIdx.x, t = threadIdx.x, g = t >> 6, l = t & 63;
    int s = off_i[n];
    int deg = off_i[n + 1] - s;
    double an = alpha[n] + consts[0];
    for (int p = t; p < deg; p += 256) {
        int e = lst_i[s + p]; int i, j; edge_ij(ei, e, i, j);
        sj[p] = j;
        double v = an + beta[j];
        ssc[p] = v > 0.0 ? v : 0.2 * v;
    }
    __syncthreads();
    if (t < 64) {
        double m = -1e300;
        for (int p = l; p < deg; p += 64) m = fmax(m, ssc[p]);
        #pragma unroll
        for (int d = 32; d > 0; d >>= 1) m = fmax(m, __shfl_xor(m, d, 64));
        double z = 0.0;
        for (int p = l; p < deg; p += 64) z += exp(ssc[p] - m);
        #pragma unroll
        for (int d = 32; d > 0; d >>= 1) z += __shfl_xor(z, d, 64);
        if (l == 0) { mz[0] = m; mz[1] = 1.0 / z; }
    }
    __syncthreads();
    double m = mz[0], inv = mz[1];
    for (int p = t; p < deg; p += 256) {
        double sc_ = exp(ssc[p] - m) * inv;
        ssc[p] = sc_;
        score32[lst_i[s + p]] = (float)sc_;
    }
    __syncthreads();
    double a0 = 0, a1 = 0, a2 = 0, a3 = 0;
    for (int p = g; p < deg; p += 4) {
        double sc_ = ssc[p];
        float4 v = ((const float4*)(x + (size_t)sj[p] * CC))[l];
        a0 += sc_ * (double)v.x; a1 += sc_ * (double)v.y;
        a2 += sc_ * (double)v.z; a3 += sc_ * (double)v.w;
    }
    red[g][4 * l + 0] = a0; red[g][4 * l + 1] = a1;
    red[g][4 * l + 2] = a2; red[g][4 * l + 3] = a3;
    __syncthreads();
    if (g == 0) {
        double o0 = red[0][4 * l] + red[1][4 * l] + red[2][4 * l] + red[3][4 * l];
        double o1 = red[0][4 * l + 1] + red[1][4 * l + 1] + red[2][4 * l + 1] + red[3][4 * l + 1];
        double o2 = red[0][4 * l + 2] + red[1][4 * l + 2] + red[2][4 * l + 2] + red[3][4 * l + 2];
        double o3 = red[0][4 * l + 3] + red[1][4 * l + 3] + red[2][4 * l + 3] + red[3][4 * l + 3];
        double* orow = out64 + (size_t)n * CC + 4 * l;
        orow[0] = o0; orow[1] = o1; orow[2] = o2; orow[3] = o3;
        float4 w1 = ((const float4*)le1_w)[l];
        float4 w2 = ((const float4*)le2_w)[l];
        float4 w3 = ((const float4*)le3_w)[l];
        double s1 = o0 * (double)w1.x + o1 * (double)w1.y + o2 * (double)w1.z + o3 * (double)w1.w;
        double s2 = o0 * (double)w2.x + o1 * (double)w2.y + o2 * (double)w2.z + o3 * (double)w2.w;
        double s3 = o0 * (double)w3.x + o1 * (double)w3.y + o2 * (double)w3.z + o3 * (double)w3.w;
        #pragma unroll
        for (int d = 32; d > 0; d >>= 1) {
            s1 += __shfl_down(s1, d, 64);
            s2 += __shfl_down(s2, d, 64);
            s3 += __shfl_down(s3, d, 64);
        }
        if (l == 0) {
            a64[n] = s1 + (double)le1_b[0];
            b64[n] = s2;
            l3v[n] = s3 + (double)le3_b[0];
        }
    }
}

__global__ __launch_bounds__(256) void k_zlog(const int* __restrict__ ei,
                                              const int* __restrict__ off_i, const int* __restrict__ lst_i,
                                              const double* __restrict__ a64, const double* __restrict__ b64,
                                              const double* __restrict__ l3v, double* zlog) {
    int n = blockIdx.x * 4 + (threadIdx.x >> 6);
    int l = threadIdx.x & 63;
    int s = off_i[n], e_ = off_i[n + 1];
    double acc = 0.0;
    for (int p = s + l; p < e_; p += 64) {
        int e = lst_i[p]; int i, j; edge_ij(ei, e, i, j);
        acc += a64[j];
    }
    #pragma unroll
    for (int d = 32; d > 0; d >>= 1) acc += __shfl_xor(acc, d, 64);
    if (l == 0) zlog[n] = acc - (double)(e_ - s) * b64[n] + l3v[n];
}

__global__ __launch_bounds__(256) void k_rank(const double* __restrict__ zlog,
                                              const double* __restrict__ out64,
                                              int* __restrict__ perm, int* __restrict__ n_idx,
                                              float* __restrict__ xout, float* __restrict__ operm) {
    int n = blockIdx.x, t = threadIdx.x;
    double zn = zlog[n];
    int cnt = 0;
    #pragma unroll
    for (int u = 0; u < NN / 256; ++u) {
        int m = t + u * 256;
        double zm = zlog[m];
        cnt += ((zm > zn) || (zm == zn && m < n)) ? 1 : 0;
    }
    #pragma unroll
    for (int d = 32; d > 0; d >>= 1) cnt += __shfl_down(cnt, d, 64);
    __shared__ int red[4];
    __shared__ int rr;
    if ((t & 63) == 0) red[t >> 6] = cnt;
    __syncthreads();
    if (t == 0) {
        int r = red[0] + red[1] + red[2] + red[3];
        rr = r;
        if (r < KK) {
            perm[r] = n;
            n_idx[n] = r;
            operm[r] = (float)n;
        }
    }
    __syncthreads();
    int r = rr;
    if (r < KK) {
        double fit = 1.0 / (1.0 + exp(-zn));
        xout[(size_t)r * CC + t] = (float)(out64[(size_t)n * CC + t] * fit);
    }
}

__global__ void k_colval(const int* __restrict__ ei, const int* __restrict__ lst_j,
                         const int* __restrict__ n_idx, const float* __restrict__ score32,
                         int* __restrict__ colj, float* __restrict__ svalj) {
    int p = blockIdx.x * 256 + threadIdx.x;
    if (p >= EE) return;
    int e = lst_j[p]; int i, j; edge_ij(ei, e, i, j);
    colj[p] = n_idx[i];
    svalj[p] = score32[e];
}

__global__ __launch_bounds__(256) void k_eadj(const int* __restrict__ ei,
                                              const int* __restrict__ off_i, const int* __restrict__ lst_i,
                                              const int* __restrict__ off_j,
                                              const int* __restrict__ perm,
                                              const float* __restrict__ score32,
                                              const int* __restrict__ colj, const float* __restrict__ svalj,
                                              float* __restrict__ Ead) {
    __shared__ float row[KK];
    int r = blockIdx.x, t = threadIdx.x;
    float4 z4 = make_float4(0.f, 0.f, 0.f, 0.f);
    for (int c = t; c < KK / 4; c += 256) ((float4*)row)[c] = z4;
    __syncthreads();
    int n = perm[r];
    int s = off_i[n], e_ = off_i[n + 1];
    int grp = t >> 5, lane = t & 31;
    for (int p = s + grp; p < e_; p += 8) {
        int e = lst_i[p]; int i, j; edge_ij(ei, e, i, j);
        float s1 = score32[e];
        int q0 = off_j[j], q1 = off_j[j + 1];
        for (int q = q0 + lane; q < q1; q += 32) {
            int c = colj[q];
            if (c >= 0) atomicAdd(&row[c], s1 * svalj[q]);
        }
    }
    __syncthreads();
    float* __restrict__ erow = Ead + (size_t)r * KK;
    for (int c4 = t; c4 < KK / 4; c4 += 256) {
        float4 v = ((float4*)row)[c4];
        int base = c4 * 4;
        int dr = r - base;
        if (dr >= 0 && dr < 4) ((float*)&v)[dr] = 1.0f;
        ((float4*)erow)[c4] = v;
    }
}

// ============================ host ============================
extern "C" void kernel_launch(void* const* d_in, const int* in_sizes, int n_in,
                              void* d_out, int out_size, void* d_ws, size_t ws_size,
                              hipStream_t stream) {
    const float* x     = (const float*)d_in[0];
    const int*   ei    = (const int*)d_in[1];
    const float* Wq    = (const float*)d_in[2];
    const float* bq    = (const float*)d_in[3];
    const float* gat_w = (const float*)d_in[4];
    const float* gat_b = (const float*)d_in[5];
    const float* le1_w = (const float*)d_in[6];
    const float* le1_b = (const float*)d_in[7];
    const float* le2_w = (const float*)d_in[8];
    const float* le3_w = (const float*)d_in[9];
    const float* le3_b = (const float*)d_in[10];

    float* xout  = (float*)d_out;          // [K, C]
    float* Ead   = xout + (size_t)KK * CC; // [K, K]
    float* operm = Ead + (size_t)KK * KK;  // [K]

    char* w = (char*)d_ws;
    auto alloc = [&](size_t bytes) -> void* {
        void* p = (void*)w;
        w += (bytes + 255) & ~(size_t)255;
        return p;
    };
    float*  score32= (float*)alloc(EE * 4);
    double* alpha  = (double*)alloc(NN * 8);   // fallback only
    double* beta   = (double*)alloc(NN * 8);   // fallback only
    double* a64    = (double*)alloc(NN * 8);
    double* b64    = (double*)alloc(NN * 8);
    double* l3v    = (double*)alloc(NN * 8);
    double* zlog   = (double*)alloc(NN * 8);
    double* out64  = (double*)alloc((size_t)NN * CC * 8);  // fallback only
    float*  out32  = (float*)alloc((size_t)NN * CC * 4);   // mega path
    double* wv     = (double*)alloc(CC * 8);
    double* consts = (double*)alloc(64);
    int* cnt_i = (int*)alloc(NN * 4);       // cnt_i, cnt_j adjacent
    int* cnt_j = (int*)alloc(NN * 4);
    int* off_i = (int*)alloc((NN + 1) * 4);
    int* pos_i = (int*)alloc(NN * 4);
    int* lst_i = (int*)alloc(EE * 4);
    int* off_j = (int*)alloc((NN + 1) * 4);
    int* pos_j = (int*)alloc(NN * 4);
    int* lst_j = (int*)alloc(EE * 4);
    int* n_idx = (int*)alloc(NN * 4);
    int* perm  = (int*)alloc(KK * 4);
    int*   colj  = (int*)alloc(EE * 4);
    float* svalj = (float*)alloc(EE * 4);

    Params P;
    P.x = x; P.ei = ei; P.Wq = Wq; P.bq = bq; P.gat_w = gat_w; P.gat_b = gat_b;
    P.le1_w = le1_w; P.le1_b = le1_b; P.le2_w = le2_w; P.le3_w = le3_w; P.le3_b = le3_b;
    P.xout = xout; P.Ead = Ead; P.operm = operm;
    P.score32 = score32; P.out32 = out32;
    P.a64 = a64; P.b64 = b64; P.l3v = l3v; P.zlog = zlog;
    P.wv = wv; P.consts = consts;
    P.cnt_i = cnt_i; P.cnt_j = cnt_j;
    P.off_i = off_i; P.pos_i = pos_i; P.lst_i = lst_i;
    P.off_j = off_j; P.pos_j = pos_j; P.lst_j = lst_j;
    P.n_idx = n_idx; P.perm = perm; P.colj = colj; P.svalj = svalj;

    void* args[] = { &P };
    hipError_t err = hipLaunchCooperativeKernel((void*)mega, dim3(NB), dim3(NT),
                                                args, 0, stream);
    if (err != hipSuccess) {
        // fallback: verified multi-kernel pipeline (identical to previous best)
        hipMemsetAsync(cnt_i, 0, 2 * NN * 4 + 256, stream);
        hipMemsetAsync(n_idx, 0xFF, NN * 4, stream);
        const int EB = (EE + 255) / 256;
        k_init<<<EB + CC, 256, 0, stream>>>(ei, cnt_i, cnt_j, Wq, bq, gat_w, gat_b, wv, consts, EB);
        k_scan<<<2, 1024, 0, stream>>>(cnt_i, off_i, pos_i, cnt_j, off_j, pos_j);
        k_scatter<<<EB, 256, 0, stream>>>(ei, pos_i, lst_i, pos_j, lst_j);
        k_xqab<<<NN, 256, 0, stream>>>(x, ei, off_i, lst_i, wv, gat_w, alpha, beta);
        k_softout<<<NN, 256, 0, stream>>>(x, ei, off_i, lst_i, alpha, beta, consts,
                                          le1_w, le1_b, le2_w, le3_w, le3_b,
                                          score32, out64, a64, b64, l3v);
        k_zlog<<<NN / 4, 256, 0, stream>>>(ei, off_i, lst_i, a64, b64, l3v, zlog);
        k_rank<<<NN, 256, 0, stream>>>(zlog, out64, perm, n_idx, xout, operm);
        k_colval<<<EB, 256, 0, stream>>>(ei, lst_j, n_idx, score32, colj, svalj);
        k_eadj<<<KK, 256, 0, stream>>>(ei, off_i, lst_i, off_j, perm, score32, colj, svalj, Ead);
    }
}

// Round 2
// 152.832 us; speedup vs baseline: 6.7363x; 6.7363x over previous
//
#include <hip/hip_runtime.h>
#include <math.h>

constexpr int NN  = 4096;   // nodes
constexpr int CC  = 256;    // channels
constexpr int EE0 = 65536;  // edges w/o self loops
constexpr int EE  = 69632;  // EE0 + NN
constexpr int KK  = 2048;   // pooled nodes
constexpr int SL  = 128;    // CSR slot stride (max degree <= 128, verified prior session)

__device__ __forceinline__ void edge_ij(const int* __restrict__ ei, int e, int& i, int& j) {
    if (e < EE0) { i = ei[e]; j = ei[EE0 + e]; }
    else         { i = e - EE0; j = i; }
}
__device__ __forceinline__ int edge_i(const int* __restrict__ ei, int e) {
    return (e < EE0) ? ei[e] : e - EE0;
}
__device__ __forceinline__ int edge_j(const int* __restrict__ ei, int e) {
    return (e < EE0) ? ei[EE0 + e] : e - EE0;
}

// ---- k_build: slotted-CSR build (count+scatter in ONE edge pass) + wv/consts ----
// blocks [0, EB): edges; blocks [EB, EB+CC): wv[k] = sum_c Wq[k,c]*gat_w[c]
__global__ __launch_bounds__(256) void k_build(const int* __restrict__ ei,
                                               int* cnt_i, int* cnt_j,
                                               int* lst_i, int* lst_j,
                                               const float* __restrict__ Wq, const float* __restrict__ bq,
                                               const float* __restrict__ gat_w, const float* __restrict__ gat_b,
                                               double* wv, double* consts, int EB) {
    if ((int)blockIdx.x < EB) {
        int e = blockIdx.x * 256 + threadIdx.x;
        if (e >= EE) return;
        int i, j; edge_ij(ei, e, i, j);
        int si = atomicAdd(&cnt_i[i], 1);
        lst_i[i * SL + si] = e;
        int sj = atomicAdd(&cnt_j[j], 1);
        lst_j[j * SL + sj] = e;
        return;
    }
    int k = blockIdx.x - EB, c = threadIdx.x, l = c & 63;
    double s = (double)Wq[k * CC + c] * (double)gat_w[c];
    #pragma unroll
    for (int d = 32; d > 0; d >>= 1) s += __shfl_down(s, d, 64);
    __shared__ double red[4];
    if (l == 0) red[c >> 6] = s;
    __syncthreads();
    if (c == 0) wv[k] = red[0] + red[1] + red[2] + red[3];
    if (k == 0 && c == 0) {
        double cb = 0.0;
        for (int q = 0; q < CC; ++q) cb += (double)bq[q] * (double)gat_w[q];
        consts[0] = cb + (double)gat_b[0];
    }
}

// ---- k_attn: fused Xq-max + per-edge beta + leakyrelu + softmax + out-gather + LEConv dots ----
// (verified numerics: identical to mega phase 4, which passed this round)
__global__ __launch_bounds__(256) void k_attn(const float* __restrict__ x, const int* __restrict__ ei,
                                              const int* __restrict__ cnt_i, const int* __restrict__ lst_i,
                                              const double* __restrict__ wv, const float* __restrict__ gat_w,
                                              const double* __restrict__ consts,
                                              const float* __restrict__ le1_w, const float* __restrict__ le1_b,
                                              const float* __restrict__ le2_w,
                                              const float* __restrict__ le3_w, const float* __restrict__ le3_b,
                                              float* __restrict__ score32, float* __restrict__ out32,
                                              double* a64, double* b64, double* l3v) {
    __shared__ int    sj[SL];
    __shared__ double ssc[SL];
    __shared__ double mz[2];
    __shared__ union { float4 m4[4][64]; double d[4][CC]; } red;

    const int n = blockIdx.x, t = threadIdx.x, g = t >> 6, l = t & 63;
    const int base = n * SL;
    const int deg = cnt_i[n];
    const float* gw2 = gat_w + CC;

    // pass A: neighbor-row max + per-edge beta dot
    float4 mx = make_float4(-INFINITY, -INFINITY, -INFINITY, -INFINITY);
    for (int p = g; p < deg; p += 4) {
        int e = lst_i[base + p];
        int j = edge_j(ei, e);
        float4 v = ((const float4*)(x + (size_t)j * CC))[l];
        mx.x = fmaxf(mx.x, v.x); mx.y = fmaxf(mx.y, v.y);
        mx.z = fmaxf(mx.z, v.z); mx.w = fmaxf(mx.w, v.w);
        double d = (double)v.x * (double)gw2[4 * l]     + (double)v.y * (double)gw2[4 * l + 1]
                 + (double)v.z * (double)gw2[4 * l + 2] + (double)v.w * (double)gw2[4 * l + 3];
        #pragma unroll
        for (int dd = 32; dd > 0; dd >>= 1) d += __shfl_down(d, dd, 64);
        if (l == 0) { sj[p] = j; ssc[p] = d; }   // beta_e
    }
    red.m4[g][l] = mx;
    __syncthreads();
    if (g == 0) {
        float4 a = red.m4[0][l], b = red.m4[1][l], c2 = red.m4[2][l], d4 = red.m4[3][l];
        float m0 = fmaxf(fmaxf(a.x, b.x), fmaxf(c2.x, d4.x));
        float m1 = fmaxf(fmaxf(a.y, b.y), fmaxf(c2.y, d4.y));
        float m2 = fmaxf(fmaxf(a.z, b.z), fmaxf(c2.z, d4.z));
        float m3 = fmaxf(fmaxf(a.w, b.w), fmaxf(c2.w, d4.w));
        double alph = (double)m0 * wv[4 * l]     + (double)m1 * wv[4 * l + 1]
                    + (double)m2 * wv[4 * l + 2] + (double)m3 * wv[4 * l + 3];
        #pragma unroll
        for (int dd = 32; dd > 0; dd >>= 1) alph += __shfl_down(alph, dd, 64);
        if (l == 0) mz[0] = alph + consts[0];
    }
    __syncthreads();
    double an = mz[0];
    for (int p = t; p < deg; p += 256) {
        double v = an + ssc[p];
        ssc[p] = v > 0.0 ? v : 0.2 * v;
    }
    __syncthreads();
    if (t < 64) {
        double mm = -1e300;
        for (int p = l; p < deg; p += 64) mm = fmax(mm, ssc[p]);
        #pragma unroll
        for (int d = 32; d > 0; d >>= 1) mm = fmax(mm, __shfl_xor(mm, d, 64));
        double z = 0.0;
        for (int p = l; p < deg; p += 64) z += exp(ssc[p] - mm);
        #pragma unroll
        for (int d = 32; d > 0; d >>= 1) z += __shfl_xor(z, d, 64);
        if (l == 0) { mz[0] = mm; mz[1] = 1.0 / z; }
    }
    __syncthreads();
    double mm = mz[0], inv = mz[1];
    for (int p = t; p < deg; p += 256) {
        double sc = exp(ssc[p] - mm) * inv;
        ssc[p] = sc;
        score32[lst_i[base + p]] = (float)sc;
    }
    __syncthreads();
    // pass B: out = sum score * x[j]
    double a0 = 0, a1 = 0, a2 = 0, a3 = 0;
    for (int p = g; p < deg; p += 4) {
        double sc = ssc[p];
        float4 v = ((const float4*)(x + (size_t)sj[p] * CC))[l];
        a0 += sc * (double)v.x; a1 += sc * (double)v.y;
        a2 += sc * (double)v.z; a3 += sc * (double)v.w;
    }
    red.d[g][4 * l + 0] = a0; red.d[g][4 * l + 1] = a1;
    red.d[g][4 * l + 2] = a2; red.d[g][4 * l + 3] = a3;
    __syncthreads();
    if (g == 0) {
        double o0 = red.d[0][4*l]   + red.d[1][4*l]   + red.d[2][4*l]   + red.d[3][4*l];
        double o1 = red.d[0][4*l+1] + red.d[1][4*l+1] + red.d[2][4*l+1] + red.d[3][4*l+1];
        double o2 = red.d[0][4*l+2] + red.d[1][4*l+2] + red.d[2][4*l+2] + red.d[3][4*l+2];
        double o3 = red.d[0][4*l+3] + red.d[1][4*l+3] + red.d[2][4*l+3] + red.d[3][4*l+3];
        float4 ov; ov.x = (float)o0; ov.y = (float)o1; ov.z = (float)o2; ov.w = (float)o3;
        ((float4*)(out32 + (size_t)n * CC))[l] = ov;
        float4 w1 = ((const float4*)le1_w)[l];
        float4 w2 = ((const float4*)le2_w)[l];
        float4 w3 = ((const float4*)le3_w)[l];
        double s1 = o0 * (double)w1.x + o1 * (double)w1.y + o2 * (double)w1.z + o3 * (double)w1.w;
        double s2 = o0 * (double)w2.x + o1 * (double)w2.y + o2 * (double)w2.z + o3 * (double)w2.w;
        double s3 = o0 * (double)w3.x + o1 * (double)w3.y + o2 * (double)w3.z + o3 * (double)w3.w;
        #pragma unroll
        for (int dd = 32; dd > 0; dd >>= 1) {
            s1 += __shfl_down(s1, dd, 64);
            s2 += __shfl_down(s2, dd, 64);
            s3 += __shfl_down(s3, dd, 64);
        }
        if (l == 0) {
            a64[n] = s1 + (double)le1_b[0];
            b64[n] = s2;
            l3v[n] = s3 + (double)le3_b[0];
        }
    }
}

// ---- k_zlog: zlog[n] = sum_e a[j_e] - deg*b[n] + l3[n]; one wave per node ----
__global__ __launch_bounds__(256) void k_zlog(const int* __restrict__ ei,
                                              const int* __restrict__ cnt_i, const int* __restrict__ lst_i,
                                              const double* __restrict__ a64, const double* __restrict__ b64,
                                              const double* __restrict__ l3v, double* zlog) {
    int n = blockIdx.x * 4 + (threadIdx.x >> 6);
    int l = threadIdx.x & 63;
    int deg = cnt_i[n];
    int base = n * SL;
    double acc = 0.0;
    for (int p = l; p < deg; p += 64) {
        int e = lst_i[base + p];
        acc += a64[edge_j(ei, e)];
    }
    #pragma unroll
    for (int d = 32; d > 0; d >>= 1) acc += __shfl_xor(acc, d, 64);
    if (l == 0) zlog[n] = acc - (double)deg * b64[n] + l3v[n];
}

// ---- k_rank: rank-by-counting top-K (stable descending), writes n_idx (incl -1) + x_out ----
__global__ __launch_bounds__(256) void k_rank(const double* __restrict__ zlog,
                                              const float* __restrict__ out32,
                                              int* __restrict__ perm, int* __restrict__ n_idx,
                                              float* __restrict__ xout, float* __restrict__ operm) {
    int n = blockIdx.x, t = threadIdx.x;
    double zn = zlog[n];
    int cnt = 0;
    #pragma unroll
    for (int u = 0; u < NN / 256; ++u) {
        int m = t + u * 256;
        double zm = zlog[m];
        cnt += ((zm > zn) || (zm == zn && m < n)) ? 1 : 0;
    }
    #pragma unroll
    for (int d = 32; d > 0; d >>= 1) cnt += __shfl_down(cnt, d, 64);
    __shared__ int red[4];
    __shared__ int rr;
    if ((t & 63) == 0) red[t >> 6] = cnt;
    __syncthreads();
    if (t == 0) {
        int r = red[0] + red[1] + red[2] + red[3];
        rr = r;
        if (r < KK) {
            perm[r] = n;
            n_idx[n] = r;
            operm[r] = (float)n;
        } else {
            n_idx[n] = -1;
        }
    }
    __syncthreads();
    int r = rr;
    if (r < KK) {
        double fit = 1.0 / (1.0 + exp(-zn));
        xout[(size_t)r * CC + t] = (float)((double)out32[(size_t)n * CC + t] * fit);
    }
}

// ---- k_colval: per slotted CSR-j slot: col = n_idx[i_e] (-1 if dropped), val = score[e] ----
__global__ __launch_bounds__(256) void k_colval(const int* __restrict__ ei,
                                                const int* __restrict__ cnt_j, const int* __restrict__ lst_j,
                                                const int* __restrict__ n_idx, const float* __restrict__ score32,
                                                int* __restrict__ colj, float* __restrict__ svalj) {
    int p = blockIdx.x * 256 + threadIdx.x;   // slot index over NN*SL
    int n = p >> 7, s = p & (SL - 1);
    if (s >= cnt_j[n]) return;
    int e = lst_j[p];
    colj[p] = n_idx[edge_i(ei, e)];
    svalj[p] = score32[e];
}

// ---- k_eadj: Eadj[r,:] accumulated in an 8KB LDS fp32 row ----
__global__ __launch_bounds__(256) void k_eadj(const int* __restrict__ ei,
                                              const int* __restrict__ cnt_i, const int* __restrict__ lst_i,
                                              const int* __restrict__ cnt_j,
                                              const int* __restrict__ perm,
                                              const float* __restrict__ score32,
                                              const int* __restrict__ colj, const float* __restrict__ svalj,
                                              float* __restrict__ Ead) {
    __shared__ float row[KK];
    int r = blockIdx.x, t = threadIdx.x;
    float4 z4 = make_float4(0.f, 0.f, 0.f, 0.f);
    for (int c = t; c < KK / 4; c += 256) ((float4*)row)[c] = z4;
    __syncthreads();
    int n = perm[r];
    int deg = cnt_i[n];
    int base = n * SL;
    int grp = t >> 5, lane = t & 31;
    for (int p = grp; p < deg; p += 8) {
        int e = lst_i[base + p];
        float s1 = score32[e];
        int j = edge_j(ei, e);
        int cj = cnt_j[j], jb = j * SL;
        for (int q = lane; q < cj; q += 32) {
            int c = colj[jb + q];
            if (c >= 0) atomicAdd(&row[c], s1 * svalj[jb + q]);
        }
    }
    __syncthreads();
    float* __restrict__ erow = Ead + (size_t)r * KK;
    for (int c4 = t; c4 < KK / 4; c4 += 256) {
        float4 v = ((float4*)row)[c4];
        int base4 = c4 * 4;
        int dr = r - base4;
        if (dr >= 0 && dr < 4) ((float*)&v)[dr] = 1.0f;
        ((float4*)erow)[c4] = v;
    }
}

// ============================ host ============================
extern "C" void kernel_launch(void* const* d_in, const int* in_sizes, int n_in,
                              void* d_out, int out_size, void* d_ws, size_t ws_size,
                              hipStream_t stream) {
    const float* x     = (const float*)d_in[0];
    const int*   ei    = (const int*)d_in[1];
    const float* Wq    = (const float*)d_in[2];
    const float* bq    = (const float*)d_in[3];
    const float* gat_w = (const float*)d_in[4];
    const float* gat_b = (const float*)d_in[5];
    const float* le1_w = (const float*)d_in[6];
    const float* le1_b = (const float*)d_in[7];
    const float* le2_w = (const float*)d_in[8];
    const float* le3_w = (const float*)d_in[9];
    const float* le3_b = (const float*)d_in[10];

    float* xout  = (float*)d_out;          // [K, C]
    float* Ead   = xout + (size_t)KK * CC; // [K, K]
    float* operm = Ead + (size_t)KK * KK;  // [K]

    char* w = (char*)d_ws;
    auto alloc = [&](size_t bytes) -> void* {
        void* p = (void*)w;
        w += (bytes + 255) & ~(size_t)255;
        return p;
    };
    float*  score32= (float*)alloc(EE * 4);
    float*  out32  = (float*)alloc((size_t)NN * CC * 4);
    double* a64    = (double*)alloc(NN * 8);
    double* b64    = (double*)alloc(NN * 8);
    double* l3v    = (double*)alloc(NN * 8);
    double* zlog   = (double*)alloc(NN * 8);
    double* wv     = (double*)alloc(CC * 8);
    double* consts = (double*)alloc(64);
    int* cnt_i = (int*)alloc(NN * 4);       // cnt_i, cnt_j adjacent: one memset
    int* cnt_j = (int*)alloc(NN * 4);
    int* lst_i = (int*)alloc((size_t)NN * SL * 4);   // slotted CSR
    int* lst_j = (int*)alloc((size_t)NN * SL * 4);
    int* n_idx = (int*)alloc(NN * 4);
    int* perm  = (int*)alloc(KK * 4);
    int*   colj  = (int*)alloc((size_t)NN * SL * 4); // slotted
    float* svalj = (float*)alloc((size_t)NN * SL * 4);

    hipMemsetAsync(cnt_i, 0, 2 * NN * 4, stream);    // cnt_i + cnt_j (adjacent)

    const int EB = (EE + 255) / 256;  // 272

    k_build<<<EB + CC, 256, 0, stream>>>(ei, cnt_i, cnt_j, lst_i, lst_j,
                                         Wq, bq, gat_w, gat_b, wv, consts, EB);
    k_attn<<<NN, 256, 0, stream>>>(x, ei, cnt_i, lst_i, wv, gat_w, consts,
                                   le1_w, le1_b, le2_w, le3_w, le3_b,
                                   score32, out32, a64, b64, l3v);
    k_zlog<<<NN / 4, 256, 0, stream>>>(ei, cnt_i, lst_i, a64, b64, l3v, zlog);
    k_rank<<<NN, 256, 0, stream>>>(zlog, out32, perm, n_idx, xout, operm);
    k_colval<<<NN * SL / 256, 256, 0, stream>>>(ei, cnt_j, lst_j, n_idx, score32, colj, svalj);
    k_eadj<<<KK, 256, 0, stream>>>(ei, cnt_i, lst_i, cnt_j, perm, score32, colj, svalj, Ead);
}